// Round 5
// baseline (427.651 us; speedup 1.0000x reference)
//
#include <hip/hip_runtime.h>

// Problem constants
#define B_ 32
#define N_ 4096
#define C_ 768
#define H_ 8
#define DH_ 96
#define S_ 32            // slices per batch row
#define RPS (N_ / S_)    // 128 rows per slice

// ---- q[e] = sum_c queries[c] * Wq[e,c] ------------------------------------
__global__ void k_q(const float* __restrict__ queries, const float* __restrict__ Wq,
                    float* __restrict__ q) {
  int e = blockIdx.x;
  int lane = threadIdx.x;
  const float* row = Wq + (size_t)e * C_;
  float acc = 0.f;
#pragma unroll
  for (int p = 0; p < 3; ++p) {
    int c = p * 256 + lane * 4;
    float4 w = *(const float4*)(row + c);
    float4 qa = *(const float4*)(queries + c);
    acc += w.x * qa.x + w.y * qa.y + w.z * qa.z + w.w * qa.w;
  }
#pragma unroll
  for (int off = 32; off; off >>= 1) acc += __shfl_xor(acc, off);
  if (lane == 0) q[e] = acc;
}

// ---- wq_eff[h,c] = sum_d q[h*DH+d] * Wkv[h*DH+d, c] -----------------------
__global__ void k_wqeff(const float* __restrict__ q, const float* __restrict__ Wkv,
                        float* __restrict__ wqe) {
  int i = blockIdx.x * 256 + threadIdx.x;
  int h = i / C_;
  int c = i - h * C_;
  const float* qh = q + h * DH_;
  float acc = 0.f;
  for (int d = 0; d < DH_; ++d)
    acc = fmaf(qh[d], Wkv[(size_t)(h * DH_ + d) * C_ + c], acc);
  wqe[i] = acc;
}

// ---- streaming fused pass: dots -> exp(d-20) -> weighted accumulate -------
// Pure-register, no LDS, no barriers. Each wave owns one (b, slice of 128
// rows). Lane owns cols {p*256 + lane*4 .. +3} for p=0,1,2.
__global__ __launch_bounds__(256, 2) void k_stream(
    const float* __restrict__ x, const float* __restrict__ wqe,
    float* __restrict__ part, float* __restrict__ spart) {
  const int lane = threadIdx.x & 63;
  const int wid  = threadIdx.x >> 6;
  const int s    = blockIdx.x * 4 + wid;     // 0..31
  const int b    = blockIdx.y;
  const int col  = lane * 4;

  // wqe resident: 96 VGPR
  float4 wq[3][H_];
#pragma unroll
  for (int p = 0; p < 3; ++p)
#pragma unroll
    for (int h = 0; h < H_; ++h)
      wq[p][h] = *(const float4*)(wqe + h * C_ + p * 256 + col);

  // accumulator: acc[j] holds head ((lane&7)^j), 96 VGPR
  float4 acc[H_][3];
#pragma unroll
  for (int j = 0; j < H_; ++j)
#pragma unroll
    for (int p = 0; p < 3; ++p)
      acc[j][p] = make_float4(0.f, 0.f, 0.f, 0.f);
  float sreg = 0.f;

  const int l1 = lane & 1, l2 = (lane >> 1) & 1, l4 = (lane >> 2) & 1;
  const float* xr = x + ((size_t)b * N_ + (size_t)s * RPS) * C_ + col;

#define LOADROW(BUF, R) do {                                        \
    const float* rp_ = xr + (size_t)(R) * C_;                       \
    BUF[0] = *(const float4*)(rp_);                                 \
    BUF[1] = *(const float4*)(rp_ + 256);                           \
    BUF[2] = *(const float4*)(rp_ + 512);                           \
  } while (0)

#define PROC(XV) do {                                               \
    float pp[H_];                                                   \
    _Pragma("unroll")                                               \
    for (int h = 0; h < H_; ++h) {                                  \
      float a_ = XV[0].x * wq[0][h].x;                              \
      a_ = fmaf(XV[0].y, wq[0][h].y, a_);                           \
      a_ = fmaf(XV[0].z, wq[0][h].z, a_);                           \
      a_ = fmaf(XV[0].w, wq[0][h].w, a_);                           \
      a_ = fmaf(XV[1].x, wq[1][h].x, a_);                           \
      a_ = fmaf(XV[1].y, wq[1][h].y, a_);                           \
      a_ = fmaf(XV[1].z, wq[1][h].z, a_);                           \
      a_ = fmaf(XV[1].w, wq[1][h].w, a_);                           \
      a_ = fmaf(XV[2].x, wq[2][h].x, a_);                           \
      a_ = fmaf(XV[2].y, wq[2][h].y, a_);                           \
      a_ = fmaf(XV[2].z, wq[2][h].z, a_);                           \
      a_ = fmaf(XV[2].w, wq[2][h].w, a_);                           \
      pp[h] = a_;                                                   \
    }                                                               \
    /* packed 8-value butterfly: lane ends with head (lane&7) */    \
    float k_, g_;                                                   \
    k_ = l1 ? pp[1] : pp[0]; g_ = l1 ? pp[0] : pp[1];               \
    float q0 = k_ + __shfl_xor(g_, 1);                              \
    k_ = l1 ? pp[3] : pp[2]; g_ = l1 ? pp[2] : pp[3];               \
    float q1 = k_ + __shfl_xor(g_, 1);                              \
    k_ = l1 ? pp[5] : pp[4]; g_ = l1 ? pp[4] : pp[5];               \
    float q2 = k_ + __shfl_xor(g_, 1);                              \
    k_ = l1 ? pp[7] : pp[6]; g_ = l1 ? pp[6] : pp[7];               \
    float q3 = k_ + __shfl_xor(g_, 1);                              \
    k_ = l2 ? q1 : q0; g_ = l2 ? q0 : q1;                           \
    float r0 = k_ + __shfl_xor(g_, 2);                              \
    k_ = l2 ? q3 : q2; g_ = l2 ? q2 : q3;                           \
    float r1 = k_ + __shfl_xor(g_, 2);                              \
    k_ = l4 ? r1 : r0; g_ = l4 ? r0 : r1;                           \
    float t_ = k_ + __shfl_xor(g_, 4);                              \
    t_ += __shfl_xor(t_, 8);                                        \
    t_ += __shfl_xor(t_, 16);                                       \
    t_ += __shfl_xor(t_, 32);                                       \
    float w_ = __expf(t_ - 20.f);                                   \
    sreg += w_;                                                     \
    float g1_ = __shfl_xor(w_, 1);                                  \
    float g2_ = __shfl_xor(w_, 2);                                  \
    float g3_ = __shfl_xor(g1_, 2);                                 \
    float g4_ = __shfl_xor(w_, 4);                                  \
    float g5_ = __shfl_xor(g1_, 4);                                 \
    float g6_ = __shfl_xor(g2_, 4);                                 \
    float g7_ = __shfl_xor(g3_, 4);                                 \
    float wj[H_] = {w_, g1_, g2_, g3_, g4_, g5_, g6_, g7_};         \
    _Pragma("unroll")                                               \
    for (int j = 0; j < H_; ++j) {                                  \
      _Pragma("unroll")                                             \
      for (int p = 0; p < 3; ++p) {                                 \
        acc[j][p].x = fmaf(wj[j], XV[p].x, acc[j][p].x);            \
        acc[j][p].y = fmaf(wj[j], XV[p].y, acc[j][p].y);            \
        acc[j][p].z = fmaf(wj[j], XV[p].z, acc[j][p].z);            \
        acc[j][p].w = fmaf(wj[j], XV[p].w, acc[j][p].w);            \
      }                                                             \
    }                                                               \
  } while (0)

  float4 bufA[3], bufB[3], bufC[3], bufD[3];
  LOADROW(bufA, 0); LOADROW(bufB, 1); LOADROW(bufC, 2); LOADROW(bufD, 3);
  for (int r = 0; r < RPS; r += 4) {
    PROC(bufA);
    PROC(bufB);
    if (r + 4 < RPS) { LOADROW(bufA, r + 4); LOADROW(bufB, r + 5); }
    PROC(bufC);
    PROC(bufD);
    if (r + 4 < RPS) { LOADROW(bufC, r + 6); LOADROW(bufD, r + 7); }
  }

  // epilogue: scatter partials (head = (lane&7)^j), plus denominators
  float* pbase = part + ((size_t)(b * S_ + s) * H_) * C_;
#pragma unroll
  for (int j = 0; j < H_; ++j) {
    int h = (lane & 7) ^ j;
#pragma unroll
    for (int p = 0; p < 3; ++p)
      *(float4*)(pbase + (size_t)h * C_ + p * 256 + col) = acc[j][p];
  }
  if (lane < H_) spart[(size_t)(b * S_ + s) * H_ + lane] = sreg;
#undef LOADROW
#undef PROC
}

// ---- combine slice partials -> xbar = sum part / sum s --------------------
__global__ __launch_bounds__(256) void k_comb(const float* __restrict__ part,
    const float* __restrict__ spart, float* __restrict__ xbar) {
  int i = blockIdx.x * 256 + threadIdx.x;   // < B*H*C
  int bh = i / C_;
  int c  = i - bh * C_;
  int b = bh / H_, h = bh - b * H_;
  const float* sp = spart + (size_t)b * S_ * H_ + h;
  const float* pp = part + ((size_t)b * S_ * H_ + h) * C_ + c;
  float denom = 0.f, acc = 0.f;
#pragma unroll 4
  for (int s = 0; s < S_; ++s) {
    denom += sp[(size_t)s * H_];
    acc   += pp[(size_t)s * H_ * C_];
  }
  xbar[i] = acc / denom;
}

// ---- out1[b,e] = sum_c xbar[b, e/DH, c] * Wkv[C+e, c] ---------------------
// grid (12, 4): weight rows register-resident, reused across 8 b.
__global__ __launch_bounds__(256) void k_out1(const float* __restrict__ xbar,
    const float* __restrict__ Wkv, float* __restrict__ out1) {
  int wv = threadIdx.x >> 6, lane = threadIdx.x & 63;
  int e0 = blockIdx.x * 64 + wv * 16;
  int b0 = blockIdx.y * 8;
  for (int it = 0; it < 16; ++it) {
    int e = e0 + it;
    int h = e / DH_;
    const float* wr = Wkv + (size_t)(C_ + e) * C_ + lane * 4;
    float4 w0 = *(const float4*)(wr);
    float4 w1 = *(const float4*)(wr + 256);
    float4 w2 = *(const float4*)(wr + 512);
    for (int bb = 0; bb < 8; ++bb) {
      int b = b0 + bb;
      const float* xr = xbar + ((size_t)b * H_ + h) * C_ + lane * 4;
      float4 x0 = *(const float4*)(xr);
      float4 x1 = *(const float4*)(xr + 256);
      float4 x2 = *(const float4*)(xr + 512);
      float a = w0.x * x0.x;
      a = fmaf(w0.y, x0.y, a); a = fmaf(w0.z, x0.z, a); a = fmaf(w0.w, x0.w, a);
      a = fmaf(w1.x, x1.x, a); a = fmaf(w1.y, x1.y, a);
      a = fmaf(w1.z, x1.z, a); a = fmaf(w1.w, x1.w, a);
      a = fmaf(w2.x, x2.x, a); a = fmaf(w2.y, x2.y, a);
      a = fmaf(w2.z, x2.z, a); a = fmaf(w2.w, x2.w, a);
#pragma unroll
      for (int off = 32; off; off >>= 1) a += __shfl_xor(a, off);
      if (lane == 0) out1[(size_t)b * C_ + e] = a;
    }
  }
}

// ---- y[b,e] = sum_c out1[b,c] * Wproj[e,c] + bproj[e] ---------------------
__global__ __launch_bounds__(256) void k_proj(const float* __restrict__ out1,
    const float* __restrict__ Wproj, const float* __restrict__ bproj,
    float* __restrict__ y) {
  int wv = threadIdx.x >> 6, lane = threadIdx.x & 63;
  int e0 = blockIdx.x * 64 + wv * 16;
  int b0 = blockIdx.y * 8;
  for (int it = 0; it < 16; ++it) {
    int e = e0 + it;
    const float* wr = Wproj + (size_t)e * C_ + lane * 4;
    float4 w0 = *(const float4*)(wr);
    float4 w1 = *(const float4*)(wr + 256);
    float4 w2 = *(const float4*)(wr + 512);
    for (int bb = 0; bb < 8; ++bb) {
      int b = b0 + bb;
      const float* xr = out1 + (size_t)b * C_ + lane * 4;
      float4 x0 = *(const float4*)(xr);
      float4 x1 = *(const float4*)(xr + 256);
      float4 x2 = *(const float4*)(xr + 512);
      float a = w0.x * x0.x;
      a = fmaf(w0.y, x0.y, a); a = fmaf(w0.z, x0.z, a); a = fmaf(w0.w, x0.w, a);
      a = fmaf(w1.x, x1.x, a); a = fmaf(w1.y, x1.y, a);
      a = fmaf(w1.z, x1.z, a); a = fmaf(w1.w, x1.w, a);
      a = fmaf(w2.x, x2.x, a); a = fmaf(w2.y, x2.y, a);
      a = fmaf(w2.z, x2.z, a); a = fmaf(w2.w, x2.w, a);
#pragma unroll
      for (int off = 32; off; off >>= 1) a += __shfl_xor(a, off);
      if (lane == 0) y[(size_t)b * C_ + e] = a + bproj[e];
    }
  }
}

extern "C" void kernel_launch(void* const* d_in, const int* in_sizes, int n_in,
                              void* d_out, int out_size, void* d_ws, size_t ws_size,
                              hipStream_t stream) {
  const float* x       = (const float*)d_in[0];
  const float* queries = (const float*)d_in[1];
  const float* Wq      = (const float*)d_in[2];
  const float* Wkv     = (const float*)d_in[3];
  const float* Wproj   = (const float*)d_in[4];
  const float* bproj   = (const float*)d_in[5];
  float* y  = (float*)d_out;
  float* ws = (float*)d_ws;

  float* q     = ws;                                   // 768
  float* wqe   = ws + 1024;                            // 6144
  float* spart = ws + 8192;                            // B*S*H = 8192
  float* part  = ws + 16384;                           // B*S*H*C = 6291456
  float* xbar  = part + (size_t)B_ * S_ * H_ * C_;     // 196608
  float* out1  = xbar + (size_t)B_ * H_ * C_;          // 24576

  hipLaunchKernelGGL(k_q,      dim3(C_),            dim3(64),  0, stream, queries, Wq, q);
  hipLaunchKernelGGL(k_wqeff,  dim3(H_ * C_ / 256), dim3(256), 0, stream, q, Wkv, wqe);
  hipLaunchKernelGGL(k_stream, dim3(S_ / 4, B_),    dim3(256), 0, stream, x, wqe, part, spart);
  hipLaunchKernelGGL(k_comb,   dim3(B_ * H_ * C_ / 256), dim3(256), 0, stream, part, spart, xbar);
  hipLaunchKernelGGL(k_out1,   dim3(12, 4),         dim3(256), 0, stream, xbar, Wkv, out1);
  hipLaunchKernelGGL(k_proj,   dim3(12, 4),         dim3(256), 0, stream, out1, Wproj, bproj, y);
}

// Round 6
// 268.659 us; speedup vs baseline: 1.5918x; 1.5918x over previous
//
#include <hip/hip_runtime.h>

// Problem constants
#define B_ 32
#define N_ 4096
#define C_ 768
#define H_ 8
#define DH_ 96
#define S_ 64            // slices per batch row
#define RPS (N_ / S_)    // 64 rows per slice

// ---- q[e] = sum_c queries[c] * Wq[e,c] ------------------------------------
__global__ void k_q(const float* __restrict__ queries, const float* __restrict__ Wq,
                    float* __restrict__ q) {
  int e = blockIdx.x;
  int lane = threadIdx.x;
  const float* row = Wq + (size_t)e * C_;
  float acc = 0.f;
#pragma unroll
  for (int p = 0; p < 3; ++p) {
    int c = p * 256 + lane * 4;
    float4 w = *(const float4*)(row + c);
    float4 qa = *(const float4*)(queries + c);
    acc += w.x * qa.x + w.y * qa.y + w.z * qa.z + w.w * qa.w;
  }
#pragma unroll
  for (int off = 32; off; off >>= 1) acc += __shfl_xor(acc, off);
  if (lane == 0) q[e] = acc;
}

// ---- wq_eff[h,c] = sum_d q[h*DH+d] * Wkv[h*DH+d, c] -----------------------
__global__ void k_wqeff(const float* __restrict__ q, const float* __restrict__ Wkv,
                        float* __restrict__ wqe) {
  int i = blockIdx.x * 256 + threadIdx.x;
  int h = i / C_;
  int c = i - h * C_;
  const float* qh = q + h * DH_;
  float acc = 0.f;
  for (int d = 0; d < DH_; ++d)
    acc = fmaf(qh[d], Wkv[(size_t)(h * DH_ + d) * C_ + c], acc);
  wqe[i] = acc;
}

// ---- streaming fused pass: dots -> exp(d-20) -> weighted accumulate -------
// Pure-register, no LDS, no barriers. Each wave owns one (b, slice of 64
// rows). Lane owns cols {p*256 + lane*4 .. +3} for p=0,1,2.
// amdgpu_waves_per_eu(2,2): pin occupancy target to 2 waves/SIMD so the
// allocator uses ~250 VGPRs instead of spilling to reach 4 waves/SIMD.
__global__ __attribute__((amdgpu_flat_work_group_size(256, 256),
                          amdgpu_waves_per_eu(2, 2))) void k_stream(
    const float* __restrict__ x, const float* __restrict__ wqe,
    float* __restrict__ part, float* __restrict__ spart) {
  const int lane = threadIdx.x & 63;
  const int wid  = threadIdx.x >> 6;
  const int s    = blockIdx.x * 4 + wid;     // 0..S_-1
  const int b    = blockIdx.y;
  const int col  = lane * 4;

  // wqe resident: 96 VGPR
  float4 wq[3][H_];
#pragma unroll
  for (int p = 0; p < 3; ++p)
#pragma unroll
    for (int h = 0; h < H_; ++h)
      wq[p][h] = *(const float4*)(wqe + h * C_ + p * 256 + col);

  // accumulator: acc[j] holds head ((lane&7)^j), 96 VGPR
  float4 acc[H_][3];
#pragma unroll
  for (int j = 0; j < H_; ++j)
#pragma unroll
    for (int p = 0; p < 3; ++p)
      acc[j][p] = make_float4(0.f, 0.f, 0.f, 0.f);
  float sreg = 0.f;

  const int l1 = lane & 1, l2 = (lane >> 1) & 1, l4 = (lane >> 2) & 1;
  const float* xr = x + ((size_t)b * N_ + (size_t)s * RPS) * C_ + col;

#define LOADROW(BUF, R) do {                                        \
    const float* rp_ = xr + (size_t)(R) * C_;                       \
    BUF[0] = *(const float4*)(rp_);                                 \
    BUF[1] = *(const float4*)(rp_ + 256);                           \
    BUF[2] = *(const float4*)(rp_ + 512);                           \
  } while (0)

#define PROC(XV) do {                                               \
    float pp[H_];                                                   \
    _Pragma("unroll")                                               \
    for (int h = 0; h < H_; ++h) {                                  \
      float a_ = XV[0].x * wq[0][h].x;                              \
      a_ = fmaf(XV[0].y, wq[0][h].y, a_);                           \
      a_ = fmaf(XV[0].z, wq[0][h].z, a_);                           \
      a_ = fmaf(XV[0].w, wq[0][h].w, a_);                           \
      a_ = fmaf(XV[1].x, wq[1][h].x, a_);                           \
      a_ = fmaf(XV[1].y, wq[1][h].y, a_);                           \
      a_ = fmaf(XV[1].z, wq[1][h].z, a_);                           \
      a_ = fmaf(XV[1].w, wq[1][h].w, a_);                           \
      a_ = fmaf(XV[2].x, wq[2][h].x, a_);                           \
      a_ = fmaf(XV[2].y, wq[2][h].y, a_);                           \
      a_ = fmaf(XV[2].z, wq[2][h].z, a_);                           \
      a_ = fmaf(XV[2].w, wq[2][h].w, a_);                           \
      pp[h] = a_;                                                   \
    }                                                               \
    /* packed 8-value butterfly: lane ends with head (lane&7) */    \
    float k_, g_;                                                   \
    k_ = l1 ? pp[1] : pp[0]; g_ = l1 ? pp[0] : pp[1];               \
    float q0 = k_ + __shfl_xor(g_, 1);                              \
    k_ = l1 ? pp[3] : pp[2]; g_ = l1 ? pp[2] : pp[3];               \
    float q1 = k_ + __shfl_xor(g_, 1);                              \
    k_ = l1 ? pp[5] : pp[4]; g_ = l1 ? pp[4] : pp[5];               \
    float q2 = k_ + __shfl_xor(g_, 1);                              \
    k_ = l1 ? pp[7] : pp[6]; g_ = l1 ? pp[6] : pp[7];               \
    float q3 = k_ + __shfl_xor(g_, 1);                              \
    k_ = l2 ? q1 : q0; g_ = l2 ? q0 : q1;                           \
    float r0 = k_ + __shfl_xor(g_, 2);                              \
    k_ = l2 ? q3 : q2; g_ = l2 ? q2 : q3;                           \
    float r1 = k_ + __shfl_xor(g_, 2);                              \
    k_ = l4 ? r1 : r0; g_ = l4 ? r0 : r1;                           \
    float t_ = k_ + __shfl_xor(g_, 4);                              \
    t_ += __shfl_xor(t_, 8);                                        \
    t_ += __shfl_xor(t_, 16);                                       \
    t_ += __shfl_xor(t_, 32);                                       \
    float w_ = __expf(t_ - 20.f);                                   \
    sreg += w_;                                                     \
    float g1_ = __shfl_xor(w_, 1);                                  \
    float g2_ = __shfl_xor(w_, 2);                                  \
    float g3_ = __shfl_xor(g1_, 2);                                 \
    float g4_ = __shfl_xor(w_, 4);                                  \
    float g5_ = __shfl_xor(g1_, 4);                                 \
    float g6_ = __shfl_xor(g2_, 4);                                 \
    float g7_ = __shfl_xor(g3_, 4);                                 \
    float wj[H_] = {w_, g1_, g2_, g3_, g4_, g5_, g6_, g7_};         \
    _Pragma("unroll")                                               \
    for (int j = 0; j < H_; ++j) {                                  \
      _Pragma("unroll")                                             \
      for (int p = 0; p < 3; ++p) {                                 \
        acc[j][p].x = fmaf(wj[j], XV[p].x, acc[j][p].x);            \
        acc[j][p].y = fmaf(wj[j], XV[p].y, acc[j][p].y);            \
        acc[j][p].z = fmaf(wj[j], XV[p].z, acc[j][p].z);            \
        acc[j][p].w = fmaf(wj[j], XV[p].w, acc[j][p].w);            \
      }                                                             \
    }                                                               \
  } while (0)

  float4 bufA[3], bufB[3];
  LOADROW(bufA, 0); LOADROW(bufB, 1);
  for (int r = 0; r < RPS; r += 2) {
    PROC(bufA);
    if (r + 2 < RPS) LOADROW(bufA, r + 2);
    PROC(bufB);
    if (r + 3 < RPS) LOADROW(bufB, r + 3);
  }

  // epilogue: scatter partials (head = (lane&7)^j), plus denominators
  float* pbase = part + ((size_t)(b * S_ + s) * H_) * C_;
#pragma unroll
  for (int j = 0; j < H_; ++j) {
    int h = (lane & 7) ^ j;
#pragma unroll
    for (int p = 0; p < 3; ++p)
      *(float4*)(pbase + (size_t)h * C_ + p * 256 + col) = acc[j][p];
  }
  if (lane < H_) spart[(size_t)(b * S_ + s) * H_ + lane] = sreg;
#undef LOADROW
#undef PROC
}

// ---- combine slice partials -> xbar = sum part / sum s --------------------
__global__ __launch_bounds__(256) void k_comb(const float* __restrict__ part,
    const float* __restrict__ spart, float* __restrict__ xbar) {
  int i = blockIdx.x * 256 + threadIdx.x;   // < B*H*C
  int bh = i / C_;
  int c  = i - bh * C_;
  int b = bh / H_, h = bh - b * H_;
  const float* sp = spart + (size_t)b * S_ * H_ + h;
  const float* pp = part + ((size_t)b * S_ * H_ + h) * C_ + c;
  float denom = 0.f, acc = 0.f;
#pragma unroll 4
  for (int s = 0; s < S_; ++s) {
    denom += sp[(size_t)s * H_];
    acc   += pp[(size_t)s * H_ * C_];
  }
  xbar[i] = acc / denom;
}

// ---- out1[b,e] = sum_c xbar[b, e/DH, c] * Wkv[C+e, c] ---------------------
// grid (12, 4): weight rows register-resident, reused across 8 b.
__global__ __launch_bounds__(256) void k_out1(const float* __restrict__ xbar,
    const float* __restrict__ Wkv, float* __restrict__ out1) {
  int wv = threadIdx.x >> 6, lane = threadIdx.x & 63;
  int e0 = blockIdx.x * 64 + wv * 16;
  int b0 = blockIdx.y * 8;
  for (int it = 0; it < 16; ++it) {
    int e = e0 + it;
    int h = e / DH_;
    const float* wr = Wkv + (size_t)(C_ + e) * C_ + lane * 4;
    float4 w0 = *(const float4*)(wr);
    float4 w1 = *(const float4*)(wr + 256);
    float4 w2 = *(const float4*)(wr + 512);
    for (int bb = 0; bb < 8; ++bb) {
      int b = b0 + bb;
      const float* xr = xbar + ((size_t)b * H_ + h) * C_ + lane * 4;
      float4 x0 = *(const float4*)(xr);
      float4 x1 = *(const float4*)(xr + 256);
      float4 x2 = *(const float4*)(xr + 512);
      float a = w0.x * x0.x;
      a = fmaf(w0.y, x0.y, a); a = fmaf(w0.z, x0.z, a); a = fmaf(w0.w, x0.w, a);
      a = fmaf(w1.x, x1.x, a); a = fmaf(w1.y, x1.y, a);
      a = fmaf(w1.z, x1.z, a); a = fmaf(w1.w, x1.w, a);
      a = fmaf(w2.x, x2.x, a); a = fmaf(w2.y, x2.y, a);
      a = fmaf(w2.z, x2.z, a); a = fmaf(w2.w, x2.w, a);
#pragma unroll
      for (int off = 32; off; off >>= 1) a += __shfl_xor(a, off);
      if (lane == 0) out1[(size_t)b * C_ + e] = a;
    }
  }
}

// ---- y[b,e] = sum_c out1[b,c] * Wproj[e,c] + bproj[e] ---------------------
__global__ __launch_bounds__(256) void k_proj(const float* __restrict__ out1,
    const float* __restrict__ Wproj, const float* __restrict__ bproj,
    float* __restrict__ y) {
  int wv = threadIdx.x >> 6, lane = threadIdx.x & 63;
  int e0 = blockIdx.x * 64 + wv * 16;
  int b0 = blockIdx.y * 8;
  for (int it = 0; it < 16; ++it) {
    int e = e0 + it;
    const float* wr = Wproj + (size_t)e * C_ + lane * 4;
    float4 w0 = *(const float4*)(wr);
    float4 w1 = *(const float4*)(wr + 256);
    float4 w2 = *(const float4*)(wr + 512);
    for (int bb = 0; bb < 8; ++bb) {
      int b = b0 + bb;
      const float* xr = out1 + (size_t)b * C_ + lane * 4;
      float4 x0 = *(const float4*)(xr);
      float4 x1 = *(const float4*)(xr + 256);
      float4 x2 = *(const float4*)(xr + 512);
      float a = w0.x * x0.x;
      a = fmaf(w0.y, x0.y, a); a = fmaf(w0.z, x0.z, a); a = fmaf(w0.w, x0.w, a);
      a = fmaf(w1.x, x1.x, a); a = fmaf(w1.y, x1.y, a);
      a = fmaf(w1.z, x1.z, a); a = fmaf(w1.w, x1.w, a);
      a = fmaf(w2.x, x2.x, a); a = fmaf(w2.y, x2.y, a);
      a = fmaf(w2.z, x2.z, a); a = fmaf(w2.w, x2.w, a);
#pragma unroll
      for (int off = 32; off; off >>= 1) a += __shfl_xor(a, off);
      if (lane == 0) y[(size_t)b * C_ + e] = a + bproj[e];
    }
  }
}

extern "C" void kernel_launch(void* const* d_in, const int* in_sizes, int n_in,
                              void* d_out, int out_size, void* d_ws, size_t ws_size,
                              hipStream_t stream) {
  const float* x       = (const float*)d_in[0];
  const float* queries = (const float*)d_in[1];
  const float* Wq      = (const float*)d_in[2];
  const float* Wkv     = (const float*)d_in[3];
  const float* Wproj   = (const float*)d_in[4];
  const float* bproj   = (const float*)d_in[5];
  float* y  = (float*)d_out;
  float* ws = (float*)d_ws;

  float* q     = ws;                                   // 768
  float* wqe   = ws + 1024;                            // 6144
  float* spart = ws + 8192;                            // B*S*H = 16384
  float* part  = ws + 32768;                           // B*S*H*C = 12582912
  float* xbar  = part + (size_t)B_ * S_ * H_ * C_;     // 196608
  float* out1  = xbar + (size_t)B_ * H_ * C_;          // 24576

  hipLaunchKernelGGL(k_q,      dim3(C_),            dim3(64),  0, stream, queries, Wq, q);
  hipLaunchKernelGGL(k_wqeff,  dim3(H_ * C_ / 256), dim3(256), 0, stream, q, Wkv, wqe);
  hipLaunchKernelGGL(k_stream, dim3(S_ / 4, B_),    dim3(256), 0, stream, x, wqe, part, spart);
  hipLaunchKernelGGL(k_comb,   dim3(B_ * H_ * C_ / 256), dim3(256), 0, stream, part, spart, xbar);
  hipLaunchKernelGGL(k_out1,   dim3(12, 4),         dim3(256), 0, stream, xbar, Wkv, out1);
  hipLaunchKernelGGL(k_proj,   dim3(12, 4),         dim3(256), 0, stream, out1, Wproj, bproj, y);
}